// Round 1
// baseline (474.936 us; speedup 1.0000x reference)
//
#include <hip/hip_runtime.h>

#define T_  8192
#define E_  256
#define BS_ 128

typedef __attribute__((ext_vector_type(8))) short bf16x8;
typedef __attribute__((ext_vector_type(4))) float f32x4;

__device__ __forceinline__ unsigned short f2bf(float x) {
    unsigned int u = __float_as_uint(x);
    u += 0x7fffu + ((u >> 16) & 1u);           // round-to-nearest-even
    return (unsigned short)(u >> 16);
}

__device__ __forceinline__ bf16x8 pack8(f32x4 a, f32x4 b) {
    bf16x8 r;
    r[0] = (short)f2bf(a[0]); r[1] = (short)f2bf(a[1]);
    r[2] = (short)f2bf(a[2]); r[3] = (short)f2bf(a[3]);
    r[4] = (short)f2bf(b[0]); r[5] = (short)f2bf(b[1]);
    r[6] = (short)f2bf(b[2]); r[7] = (short)f2bf(b[3]);
    return r;
}

// ---------------- Kernel 1: S = QK^T * scale, causal mask, softmax -> A (fp32) ----
// One WG per (batch, block) tile. 256 threads = 4 waves; wave w owns S rows [32w,32w+32).
// K tile staged to LDS as bf16, row-major, 16B chunks XOR-swizzled by (row&15) so both
// staging writes and ds_read_b128 fragment reads are bank-conflict-free-ish.
// Q fragments are read directly from global (each row read exactly once, coalesced).
__global__ __launch_bounds__(256, 2) void dba_qk_softmax(
        const float* __restrict__ Qg, const float* __restrict__ Kg,
        float* __restrict__ Ag)
{
    __shared__ unsigned short Ks[BS_ * E_];   // 128 rows x 256 bf16 = 64 KB

    const int tid  = threadIdx.x;
    const int lane = tid & 63;
    const int w    = tid >> 6;     // wave 0..3
    const int cl   = lane & 15;    // col-in-tile (C layout) / m (A layout) / n (B layout)
    const int g    = lane >> 4;    // quad group 0..3
    const int bi   = blockIdx.x >> 6;
    const int ni   = blockIdx.x & 63;
    const int base  = (bi * T_ + ni * BS_) * E_;
    const int abase = (bi * T_ + ni * BS_) * BS_;

    // ---- stage K: fp32 global -> bf16 LDS ----
    {
        const int kq   = (tid & 63) * 4;      // col 0..252 step 4 (within one 8-chunk half)
        const int nhi  = tid >> 6;            // 0..3
        const int chnk = kq >> 3;
        const int klow = kq & 7;              // 0 or 4
        #pragma unroll 8
        for (int i = 0; i < 32; ++i) {
            const int n = i * 4 + nhi;        // key row 0..127
            f32x4 kv = *(const f32x4*)(Kg + base + n * E_ + kq);
            const int chunkp = chnk ^ (n & 15);
            uint2 pk;
            pk.x = (unsigned)f2bf(kv[0]) | ((unsigned)f2bf(kv[1]) << 16);
            pk.y = (unsigned)f2bf(kv[2]) | ((unsigned)f2bf(kv[3]) << 16);
            *(uint2*)&Ks[n * E_ + chunkp * 8 + klow] = pk;
        }
    }
    __syncthreads();

    // ---- S = Q K^T via mfma_f32_16x16x32_bf16 ----
    // wave computes 2 row-tiles (rt) x 8 col-tiles (nt) of 16x16
    f32x4 acc[2][8];
    #pragma unroll
    for (int rt = 0; rt < 2; ++rt)
        #pragma unroll
        for (int nt = 0; nt < 8; ++nt)
            acc[rt][nt] = (f32x4){0.f, 0.f, 0.f, 0.f};

    const float* q0p = Qg + base + (w * 32 + cl) * E_;        // A-frag row, rt=0
    const float* q1p = q0p + 16 * E_;                         // rt=1
    f32x4 q00 = *(const f32x4*)(q0p + g * 8);
    f32x4 q01 = *(const f32x4*)(q0p + g * 8 + 4);
    f32x4 q10 = *(const f32x4*)(q1p + g * 8);
    f32x4 q11 = *(const f32x4*)(q1p + g * 8 + 4);

    for (int ks = 0; ks < 8; ++ks) {          // K dim: 8 steps of 32
        bf16x8 aq0 = pack8(q00, q01);
        bf16x8 aq1 = pack8(q10, q11);
        if (ks < 7) {                          // prefetch next Q fragment
            const int kn = (ks + 1) * 32 + g * 8;
            q00 = *(const f32x4*)(q0p + kn);
            q01 = *(const f32x4*)(q0p + kn + 4);
            q10 = *(const f32x4*)(q1p + kn);
            q11 = *(const f32x4*)(q1p + kn + 4);
        }
        const int chunkp = (ks * 4 + g) ^ cl;  // swizzled chunk (row&15 == cl)
        #pragma unroll
        for (int nt = 0; nt < 8; ++nt) {
            const int n = nt * 16 + cl;        // key row
            bf16x8 bk = *(const bf16x8*)&Ks[n * E_ + chunkp * 8];
            acc[0][nt] = __builtin_amdgcn_mfma_f32_16x16x32_bf16(aq0, bk, acc[0][nt], 0, 0, 0);
            acc[1][nt] = __builtin_amdgcn_mfma_f32_16x16x32_bf16(aq1, bk, acc[1][nt], 0, 0, 0);
        }
    }

    // ---- mask + softmax. C layout: col = cl (+16*nt), row = 4*g + reg (+16*rt +32*w) ----
    const float scale = 0.0625f;               // 1/sqrt(256)
    const float L2E   = 1.4426950408889634f;
    #pragma unroll
    for (int rt = 0; rt < 2; ++rt) {
        #pragma unroll
        for (int r = 0; r < 4; ++r) {
            const int q = w * 32 + rt * 16 + g * 4 + r;   // local query row
            float m = -__builtin_inff();
            #pragma unroll
            for (int nt = 0; nt < 8; ++nt) {
                const int c = nt * 16 + cl;                // local key col
                float z = acc[rt][nt][r] * scale;
                z = (c > q) ? -__builtin_inff() : z;       // causal mask
                acc[rt][nt][r] = z;
                m = fmaxf(m, z);
            }
            // row lives across the 16 lanes sharing g: butterfly within 16-lane group
            m = fmaxf(m, __shfl_xor(m, 1));
            m = fmaxf(m, __shfl_xor(m, 2));
            m = fmaxf(m, __shfl_xor(m, 4));
            m = fmaxf(m, __shfl_xor(m, 8));
            float s = 0.f;
            #pragma unroll
            for (int nt = 0; nt < 8; ++nt) {
                const float p = exp2f((acc[rt][nt][r] - m) * L2E);  // exp(z-m); -inf -> 0
                acc[rt][nt][r] = p;
                s += p;
            }
            s += __shfl_xor(s, 1);
            s += __shfl_xor(s, 2);
            s += __shfl_xor(s, 4);
            s += __shfl_xor(s, 8);
            const float rinv = __builtin_amdgcn_rcpf(s);   // s >= 1, ~1ulp is plenty
            #pragma unroll
            for (int nt = 0; nt < 8; ++nt)
                acc[rt][nt][r] *= rinv;
        }
    }

    // ---- store A (fp32). This IS output #2 AND the operand store for kernel 2. ----
    #pragma unroll
    for (int rt = 0; rt < 2; ++rt)
        #pragma unroll
        for (int nt = 0; nt < 8; ++nt)
            #pragma unroll
            for (int r = 0; r < 4; ++r)
                Ag[abase + (w * 32 + rt * 16 + g * 4 + r) * BS_ + nt * 16 + cl] = acc[rt][nt][r];
}

// ---------------- Kernel 2: O = A * V ------------------------------------------
// A-frags read from global (rows just written by kernel 1; L3-resident).
// V staged to LDS transposed (V^T[n][k]) so B-frags are contiguous ds_read_b128.
__global__ __launch_bounds__(256, 2) void dba_av(
        const float* __restrict__ Ag, const float* __restrict__ Vg,
        float* __restrict__ Og)
{
    __shared__ unsigned short Vs[E_ * BS_];   // V^T: 256 rows(n) x 128 bf16(k) = 64 KB

    const int tid  = threadIdx.x;
    const int lane = tid & 63;
    const int w    = tid >> 6;
    const int cl   = lane & 15;
    const int g    = lane >> 4;
    const int bi   = blockIdx.x >> 6;
    const int ni   = blockIdx.x & 63;
    const int base  = (bi * T_ + ni * BS_) * E_;
    const int abase = (bi * T_ + ni * BS_) * BS_;

    // ---- stage V^T: thread t owns column n=t; global reads stay 256B-coalesced ----
    {
        const int n  = tid;                   // V column 0..255
        const int nx = n & 15;
        #pragma unroll 8
        for (int i = 0; i < 32; ++i) {
            const int k = i * 4;              // V row (contraction index)
            const float* vp = Vg + base + k * E_ + n;
            const float v0 = vp[0];
            const float v1 = vp[E_];
            const float v2 = vp[2 * E_];
            const float v3 = vp[3 * E_];
            const int chunkp = (k >> 3) ^ nx;
            uint2 pk;
            pk.x = (unsigned)f2bf(v0) | ((unsigned)f2bf(v1) << 16);
            pk.y = (unsigned)f2bf(v2) | ((unsigned)f2bf(v3) << 16);
            *(uint2*)&Vs[n * BS_ + chunkp * 8 + (k & 7)] = pk;
        }
    }
    __syncthreads();

    // ---- O(128x256) = A(128x128) * V(128x256): 2 rt x 16 nt tiles, 4 k-steps ----
    f32x4 acc[2][16];
    #pragma unroll
    for (int rt = 0; rt < 2; ++rt)
        #pragma unroll
        for (int nt = 0; nt < 16; ++nt)
            acc[rt][nt] = (f32x4){0.f, 0.f, 0.f, 0.f};

    const float* a0p = Ag + abase + (w * 32 + cl) * BS_;
    const float* a1p = a0p + 16 * BS_;
    f32x4 a00 = *(const f32x4*)(a0p + g * 8);
    f32x4 a01 = *(const f32x4*)(a0p + g * 8 + 4);
    f32x4 a10 = *(const f32x4*)(a1p + g * 8);
    f32x4 a11 = *(const f32x4*)(a1p + g * 8 + 4);

    for (int ks = 0; ks < 4; ++ks) {
        bf16x8 fa0 = pack8(a00, a01);
        bf16x8 fa1 = pack8(a10, a11);
        if (ks < 3) {
            const int kn = (ks + 1) * 32 + g * 8;
            a00 = *(const f32x4*)(a0p + kn);
            a01 = *(const f32x4*)(a0p + kn + 4);
            a10 = *(const f32x4*)(a1p + kn);
            a11 = *(const f32x4*)(a1p + kn + 4);
        }
        const int chunkp = (ks * 4 + g) ^ cl;
        #pragma unroll
        for (int nt = 0; nt < 16; ++nt) {
            const int nn = nt * 16 + cl;       // output column
            bf16x8 bv = *(const bf16x8*)&Vs[nn * BS_ + chunkp * 8];
            acc[0][nt] = __builtin_amdgcn_mfma_f32_16x16x32_bf16(fa0, bv, acc[0][nt], 0, 0, 0);
            acc[1][nt] = __builtin_amdgcn_mfma_f32_16x16x32_bf16(fa1, bv, acc[1][nt], 0, 0, 0);
        }
    }

    #pragma unroll
    for (int rt = 0; rt < 2; ++rt)
        #pragma unroll
        for (int nt = 0; nt < 16; ++nt)
            #pragma unroll
            for (int r = 0; r < 4; ++r)
                Og[base + (w * 32 + rt * 16 + g * 4 + r) * E_ + nt * 16 + cl] = acc[rt][nt][r];
}

extern "C" void kernel_launch(void* const* d_in, const int* in_sizes, int n_in,
                              void* d_out, int out_size, void* d_ws, size_t ws_size,
                              hipStream_t stream) {
    const float* Q = (const float*)d_in[0];
    const float* K = (const float*)d_in[1];
    const float* V = (const float*)d_in[2];
    float* O = (float*)d_out;
    const int b = in_sizes[0] / (T_ * E_);            // 16
    float* A = O + (size_t)b * T_ * E_;               // output #2 region of d_out
    dim3 grid(b * (T_ / BS_));                        // 1024 tiles
    dim3 block(256);
    dba_qk_softmax<<<grid, block, 0, stream>>>(Q, K, A);
    dba_av<<<grid, block, 0, stream>>>(A, V, O);
}

// Round 2
// 439.491 us; speedup vs baseline: 1.0807x; 1.0807x over previous
//
#include <hip/hip_runtime.h>

#define T_  8192
#define E_  256
#define BS_ 128

typedef __attribute__((ext_vector_type(8))) short bf16x8;
typedef __attribute__((ext_vector_type(4))) float f32x4;

__device__ __forceinline__ unsigned short f2bf(float x) {
    unsigned int u = __float_as_uint(x);
    u += 0x7fffu + ((u >> 16) & 1u);           // round-to-nearest-even
    return (unsigned short)(u >> 16);
}

__device__ __forceinline__ bf16x8 pack8(f32x4 a, f32x4 b) {
    bf16x8 r;
    r[0] = (short)f2bf(a[0]); r[1] = (short)f2bf(a[1]);
    r[2] = (short)f2bf(a[2]); r[3] = (short)f2bf(a[3]);
    r[4] = (short)f2bf(b[0]); r[5] = (short)f2bf(b[1]);
    r[6] = (short)f2bf(b[2]); r[7] = (short)f2bf(b[3]);
    return r;
}

// Fused diag-block attention: one WG per (batch, block) tile, 512 threads = 8 waves.
// Wave w owns S/O rows [16w, 16w+16). 64 KB LDS buffer holds K (bf16, swizzled),
// is re-used for V^T after a barrier. A (fp32, mandatory output) is stored to
// global and read straight back for the PV GEMM (same WG -> L1/L2-hot), which
// doubles as the C-layout -> A-layout transpose.
// __launch_bounds__(512,4): 16 waves/CU (2 blocks x 8 waves), VGPR <= 128.
__global__ __launch_bounds__(512, 4) void dba_fused(
        const float* __restrict__ Qg, const float* __restrict__ Kg,
        const float* __restrict__ Vg, float* __restrict__ Ag,
        float* __restrict__ Og)
{
    __shared__ unsigned short Sm[BS_ * E_];   // 64 KB: K[128][256] bf16, then V^T[256][128] bf16

    const int tid  = threadIdx.x;
    const int lane = tid & 63;
    const int w    = tid >> 6;     // wave 0..7
    const int cl   = lane & 15;    // col (C layout) / m (A layout) / n (B layout)
    const int g    = lane >> 4;    // quad group 0..3
    const int bi   = blockIdx.x >> 6;
    const int ni   = blockIdx.x & 63;
    const int base  = (bi * T_ + ni * BS_) * E_;
    const int abase = (bi * T_ + ni * BS_) * BS_;

    // ---- stage K: fp32 global -> bf16 LDS, 16B-chunk XOR swizzle by (row&15) ----
    {
        const int c4   = lane * 4;            // col 0..252 step 4
        const int chnk = c4 >> 3;
        const int klow = c4 & 7;              // 0 or 4
        #pragma unroll 4
        for (int i = 0; i < 16; ++i) {
            const int n = i * 8 + w;          // key row 0..127
            f32x4 kv = __builtin_nontemporal_load((const f32x4*)(Kg + base + n * E_ + c4));
            const int cp = chnk ^ (n & 15);
            uint2 pk;
            pk.x = (unsigned)f2bf(kv[0]) | ((unsigned)f2bf(kv[1]) << 16);
            pk.y = (unsigned)f2bf(kv[2]) | ((unsigned)f2bf(kv[3]) << 16);
            *(uint2*)&Sm[n * E_ + cp * 8 + klow] = pk;
        }
    }
    __syncthreads();

    // ---- S = Q K^T via mfma_f32_16x16x32_bf16; wave w: 1 row-tile x 8 col-tiles ----
    f32x4 acc[8];
    #pragma unroll
    for (int nt = 0; nt < 8; ++nt) acc[nt] = (f32x4){0.f, 0.f, 0.f, 0.f};

    const float* qp = Qg + base + (w * 16 + cl) * E_;         // A-frag row
    f32x4 q0 = __builtin_nontemporal_load((const f32x4*)(qp + g * 8));
    f32x4 q1 = __builtin_nontemporal_load((const f32x4*)(qp + g * 8 + 4));

    for (int ks = 0; ks < 8; ++ks) {          // contraction: 8 steps of 32
        bf16x8 aq = pack8(q0, q1);
        if (ks < 7) {
            const int kn = (ks + 1) * 32 + g * 8;
            q0 = __builtin_nontemporal_load((const f32x4*)(qp + kn));
            q1 = __builtin_nontemporal_load((const f32x4*)(qp + kn + 4));
        }
        #pragma unroll
        for (int nt = 0; nt < 8; ++nt) {
            const int n  = nt * 16 + cl;      // key row
            const int cp = (ks * 4 + g) ^ cl;
            bf16x8 bk = *(const bf16x8*)&Sm[n * E_ + cp * 8];
            acc[nt] = __builtin_amdgcn_mfma_f32_16x16x32_bf16(aq, bk, acc[nt], 0, 0, 0);
        }
    }

    // ---- mask + softmax. C layout: col = 16*nt + cl, row = 16*w + 4*g + r ----
    const float scale = 0.0625f;               // 1/sqrt(256)
    const float L2E   = 1.4426950408889634f;
    #pragma unroll
    for (int r = 0; r < 4; ++r) {
        const int q = w * 16 + g * 4 + r;      // local query row
        float m = -__builtin_inff();
        #pragma unroll
        for (int nt = 0; nt < 8; ++nt) {
            const int c = nt * 16 + cl;
            float z = acc[nt][r] * scale;
            z = (c > q) ? -__builtin_inff() : z;
            acc[nt][r] = z;
            m = fmaxf(m, z);
        }
        m = fmaxf(m, __shfl_xor(m, 1));
        m = fmaxf(m, __shfl_xor(m, 2));
        m = fmaxf(m, __shfl_xor(m, 4));
        m = fmaxf(m, __shfl_xor(m, 8));
        float s = 0.f;
        #pragma unroll
        for (int nt = 0; nt < 8; ++nt) {
            const float p = exp2f((acc[nt][r] - m) * L2E);
            acc[nt][r] = p;
            s += p;
        }
        s += __shfl_xor(s, 1);
        s += __shfl_xor(s, 2);
        s += __shfl_xor(s, 4);
        s += __shfl_xor(s, 8);
        const float rinv = __builtin_amdgcn_rcpf(s);
        #pragma unroll
        for (int nt = 0; nt < 8; ++nt)
            acc[nt][r] *= rinv;
    }

    // ---- store A (fp32): output #2 AND the transpose staging for the PV GEMM ----
    #pragma unroll
    for (int nt = 0; nt < 8; ++nt)
        #pragma unroll
        for (int r = 0; r < 4; ++r)
            Ag[abase + (w * 16 + g * 4 + r) * BS_ + nt * 16 + cl] = acc[nt][r];

    __syncthreads();   // K-LDS reads done + A stores visible WG-wide

    // ---- stage V^T into the same LDS: Vs[n=V-col][k=V-row] bf16, swizzled ----
    {
        const int n  = tid & 255;              // V column 0..255
        const int kh = (tid >> 8) * 64;        // k half
        const int nx = n & 15;
        #pragma unroll 4
        for (int i = 0; i < 16; ++i) {
            const int k = kh + i * 4;          // V row (contraction index)
            const float* vp = Vg + base + k * E_ + n;
            const float v0 = __builtin_nontemporal_load(vp);
            const float v1 = __builtin_nontemporal_load(vp + E_);
            const float v2 = __builtin_nontemporal_load(vp + 2 * E_);
            const float v3 = __builtin_nontemporal_load(vp + 3 * E_);
            const int cp = (k >> 3) ^ nx;
            uint2 pk;
            pk.x = (unsigned)f2bf(v0) | ((unsigned)f2bf(v1) << 16);
            pk.y = (unsigned)f2bf(v2) | ((unsigned)f2bf(v3) << 16);
            *(uint2*)&Sm[n * BS_ + cp * 8 + (k & 7)] = pk;
        }
    }
    __syncthreads();

    // ---- O = A * V: wave w rows [16w,16w+16), 16 col-tiles, 4 k-steps ----
    f32x4 acc2[16];
    #pragma unroll
    for (int nt = 0; nt < 16; ++nt) acc2[nt] = (f32x4){0.f, 0.f, 0.f, 0.f};

    const float* ap = Ag + abase + (w * 16 + cl) * BS_;
    f32x4 a0 = *(const f32x4*)(ap + g * 8);
    f32x4 a1 = *(const f32x4*)(ap + g * 8 + 4);

    for (int ks = 0; ks < 4; ++ks) {
        bf16x8 fa = pack8(a0, a1);
        if (ks < 3) {
            const int kn = (ks + 1) * 32 + g * 8;
            a0 = *(const f32x4*)(ap + kn);
            a1 = *(const f32x4*)(ap + kn + 4);
        }
        #pragma unroll
        for (int nt = 0; nt < 16; ++nt) {
            const int nn = nt * 16 + cl;       // output column
            const int cp = (ks * 4 + g) ^ cl;
            bf16x8 bv = *(const bf16x8*)&Sm[nn * BS_ + cp * 8];
            acc2[nt] = __builtin_amdgcn_mfma_f32_16x16x32_bf16(fa, bv, acc2[nt], 0, 0, 0);
        }
    }

    #pragma unroll
    for (int nt = 0; nt < 16; ++nt)
        #pragma unroll
        for (int r = 0; r < 4; ++r)
            __builtin_nontemporal_store(acc2[nt][r],
                Og + base + (w * 16 + g * 4 + r) * E_ + nt * 16 + cl);
}

extern "C" void kernel_launch(void* const* d_in, const int* in_sizes, int n_in,
                              void* d_out, int out_size, void* d_ws, size_t ws_size,
                              hipStream_t stream) {
    const float* Q = (const float*)d_in[0];
    const float* K = (const float*)d_in[1];
    const float* V = (const float*)d_in[2];
    float* O = (float*)d_out;
    const int b = in_sizes[0] / (T_ * E_);            // 16
    float* A = O + (size_t)b * T_ * E_;               // output #2 region of d_out
    dim3 grid(b * (T_ / BS_));                        // 1024 tiles
    dim3 block(512);
    dba_fused<<<grid, block, 0, stream>>>(Q, K, V, A, O);
}